// Round 1
// baseline (728.203 us; speedup 1.0000x reference)
//
#include <hip/hip_runtime.h>
#include <stdint.h>

#define LDIM 512
#define LLTOT 262144            // 512*512
#define EPSV 1e-5f

// Per guide §3: bf16 16x16x32 fragment = 8 bf16 in 4 VGPRs (ext_vector of short)
typedef short bf16x8 __attribute__((ext_vector_type(8)));
typedef float f32x4 __attribute__((ext_vector_type(4)));

__device__ __forceinline__ unsigned short f2bf(float f) {
  union { float f; unsigned u; } v; v.f = f;
  unsigned r = v.u + 0x7FFFu + ((v.u >> 16) & 1u);   // RNE
  return (unsigned short)(r >> 16);
}
__device__ __forceinline__ float bf2f(unsigned short h) {
  union { unsigned u; float f; } v; v.u = ((unsigned)h) << 16;
  return v.f;
}
__device__ __forceinline__ float sigm(float x) { return 1.0f / (1.0f + __expf(-x)); }

// ---------------------------------------------------------------------------
// K0: weights fp32 [c][o] -> bf16 transposed [o][c].  Order: ga,pa,gb,pb,go,po
// ---------------------------------------------------------------------------
__global__ void k_prep(const float* __restrict__ Wpa, const float* __restrict__ Wga,
                       const float* __restrict__ Wpb, const float* __restrict__ Wgb,
                       const float* __restrict__ Wgo, const float* __restrict__ Wpo,
                       unsigned short* __restrict__ Wt) {
  int t = blockIdx.x * blockDim.x + threadIdx.x;     // 0..98303
  int mat = t >> 14;
  int rem = t & 16383;
  int o = rem >> 7;
  int c = rem & 127;
  const float* src;
  switch (mat) {
    case 0: src = Wga; break;
    case 1: src = Wpa; break;
    case 2: src = Wgb; break;
    case 3: src = Wpb; break;
    case 4: src = Wgo; break;
    default: src = Wpo; break;
  }
  Wt[mat * 16384 + o * 128 + c] = f2bf(src[c * 128 + o]);
}

// ---------------------------------------------------------------------------
// K1: LayerNorm(z) -> z_ln bf16 [row][c].  One row (128 ch) per wave.
// ---------------------------------------------------------------------------
__global__ __launch_bounds__(256) void k_ln_in(const float* __restrict__ z,
                                               const float* __restrict__ w,
                                               const float* __restrict__ b,
                                               unsigned short* __restrict__ zln) {
  int wave = (blockIdx.x * blockDim.x + threadIdx.x) >> 6;
  int lane = threadIdx.x & 63;
  const float2* zp = (const float2*)(z + wave * 128);
  float2 v = zp[lane];
  float s = v.x + v.y;
  float q = v.x * v.x + v.y * v.y;
#pragma unroll
  for (int off = 32; off; off >>= 1) { s += __shfl_xor(s, off); q += __shfl_xor(q, off); }
  float mu = s * (1.0f / 128.0f);
  float var = q * (1.0f / 128.0f) - mu * mu;
  float rs = rsqrtf(var + EPSV);
  float w0 = w[2 * lane], w1 = w[2 * lane + 1];
  float b0 = b[2 * lane], b1 = b[2 * lane + 1];
  ushort2 o;
  o.x = f2bf((v.x - mu) * rs * w0 + b0);
  o.y = f2bf((v.y - mu) * rs * w1 + b1);
  ((ushort2*)(zln + wave * 128))[lane] = o;
}

// ---------------------------------------------------------------------------
// K2: fused projections.  Per block: 128 rows.
//  a = sigmoid(zln@Wga)*(zln@Wpa)*mask  -> a_t[c][row]  (channel-major, bf16)
//  b = ... -> b_t[c][row];  g = sigmoid(zln@Wgo) -> g[row][c] (bf16)
// ---------------------------------------------------------------------------
__global__ __launch_bounds__(256) void k_proj(const unsigned short* __restrict__ zln,
                                              const unsigned short* __restrict__ Wt,
                                              const int* __restrict__ maskp,
                                              unsigned short* __restrict__ a_t,
                                              unsigned short* __restrict__ b_t,
                                              unsigned short* __restrict__ gout) {
  __shared__ unsigned char zbuf[128 * 272];   // rows padded 256->272B (bank spread)
  __shared__ float maskf[128];
  const int t = threadIdx.x;
  const long r0 = (long)blockIdx.x * 128;

  {  // stage zln tile (contiguous 32 KB -> padded LDS rows)
    const char* gsrc = (const char*)zln + r0 * 256;
#pragma unroll
    for (int it = 0; it < 8; ++it) {
      int chunk = it * 256 + t;
      int row = chunk >> 4, cc = chunk & 15;
      *(int4*)(&zbuf[row * 272 + cc * 16]) = *(const int4*)(gsrc + row * 256 + cc * 16);
    }
  }
  if (t < 128) maskf[t] = (float)maskp[r0 + t];
  __syncthreads();

  const int w = t >> 6, lane = t & 63;
  const int mn = lane & 15, q4 = lane >> 4;

  // whole A-tile of this wave (32 rows x 128 k) in registers
  bf16x8 afr[2][4];
#pragma unroll
  for (int mt = 0; mt < 2; ++mt)
#pragma unroll
    for (int kk = 0; kk < 4; ++kk)
      afr[mt][kk] = *(const bf16x8*)(&zbuf[(w * 32 + mt * 16 + mn) * 272 + kk * 64 + q4 * 16]);
  __syncthreads();   // zbuf reusable (g bounce below)

#pragma unroll 1
  for (int p = 0; p < 2; ++p) {
    const unsigned short* Wg = Wt + (p * 2) * 16384;
    const unsigned short* Wp = Wt + (p * 2 + 1) * 16384;
    unsigned short* dst = p ? b_t : a_t;
#pragma unroll 1
    for (int nt = 0; nt < 8; ++nt) {
      f32x4 aG0 = {0.f,0.f,0.f,0.f}, aG1 = {0.f,0.f,0.f,0.f};
      f32x4 aP0 = {0.f,0.f,0.f,0.f}, aP1 = {0.f,0.f,0.f,0.f};
#pragma unroll
      for (int kk = 0; kk < 4; ++kk) {
        bf16x8 bg = *(const bf16x8*)(Wg + (nt * 16 + mn) * 128 + kk * 32 + q4 * 8);
        bf16x8 bp = *(const bf16x8*)(Wp + (nt * 16 + mn) * 128 + kk * 32 + q4 * 8);
        aG0 = __builtin_amdgcn_mfma_f32_16x16x32_bf16(afr[0][kk], bg, aG0, 0, 0, 0);
        aG1 = __builtin_amdgcn_mfma_f32_16x16x32_bf16(afr[1][kk], bg, aG1, 0, 0, 0);
        aP0 = __builtin_amdgcn_mfma_f32_16x16x32_bf16(afr[0][kk], bp, aP0, 0, 0, 0);
        aP1 = __builtin_amdgcn_mfma_f32_16x16x32_bf16(afr[1][kk], bp, aP1, 0, 0, 0);
      }
      const int c = nt * 16 + mn;
#pragma unroll
      for (int mt = 0; mt < 2; ++mt) {
        const f32x4 vG = mt ? aG1 : aG0;
        const f32x4 vP = mt ? aP1 : aP0;
        const int rowb = w * 32 + mt * 16 + q4 * 4;
        unsigned short hv[4];
#pragma unroll
        for (int r = 0; r < 4; ++r)
          hv[r] = f2bf(sigm(vG[r]) * vP[r] * maskf[rowb + r]);
        uint2 pk;
        pk.x = (unsigned)hv[0] | ((unsigned)hv[1] << 16);
        pk.y = (unsigned)hv[2] | ((unsigned)hv[3] << 16);
        *(uint2*)(dst + (long)c * LLTOT + r0 + rowb) = pk;   // 4 contig rows of a_t[c]
      }
    }
  }

  {  // g = sigmoid(zln @ Wgo), bounce via zbuf for coalesced [row][c] store
    const unsigned short* Wg = Wt + 4 * 16384;
#pragma unroll 1
    for (int nt = 0; nt < 8; ++nt) {
      f32x4 aG0 = {0.f,0.f,0.f,0.f}, aG1 = {0.f,0.f,0.f,0.f};
#pragma unroll
      for (int kk = 0; kk < 4; ++kk) {
        bf16x8 bg = *(const bf16x8*)(Wg + (nt * 16 + mn) * 128 + kk * 32 + q4 * 8);
        aG0 = __builtin_amdgcn_mfma_f32_16x16x32_bf16(afr[0][kk], bg, aG0, 0, 0, 0);
        aG1 = __builtin_amdgcn_mfma_f32_16x16x32_bf16(afr[1][kk], bg, aG1, 0, 0, 0);
      }
      const int c = nt * 16 + mn;
#pragma unroll
      for (int mt = 0; mt < 2; ++mt) {
        const f32x4 vG = mt ? aG1 : aG0;
        const int rowb = w * 32 + mt * 16 + q4 * 4;
#pragma unroll
        for (int r = 0; r < 4; ++r)
          *(unsigned short*)(&zbuf[(rowb + r) * 272 + c * 2]) = f2bf(sigm(vG[r]));
      }
    }
  }
  __syncthreads();
  {
    char* gdst = (char*)gout + r0 * 256;
#pragma unroll
    for (int it = 0; it < 8; ++it) {
      int chunk = it * 256 + t;
      int row = chunk >> 4, cc = chunk & 15;
      *(int4*)(gdst + row * 256 + cc * 16) = *(const int4*)(&zbuf[row * 272 + cc * 16]);
    }
  }
}

// ---------------------------------------------------------------------------
// K3: per-channel GEMM  m_c = a_c @ b_c^T  (both [512][512] bf16 row-major,
// k-contiguous).  128x128 tile per block, BK=64, XOR-swizzled LDS.
// ---------------------------------------------------------------------------
__global__ __launch_bounds__(256) void k_einsum(const unsigned short* __restrict__ a_t,
                                                const unsigned short* __restrict__ b_t,
                                                unsigned short* __restrict__ m_t) {
  __shared__ unsigned char shm[36864];   // A 16K + B 16K; epilogue: 4 x 9216B
  unsigned char* Abuf = shm;
  unsigned char* Bbuf = shm + 16384;
  const int t = threadIdx.x;
  const int w = t >> 6, lane = t & 63;
  const int ch = blockIdx.y;
  const int ti = blockIdx.x >> 2, tj = blockIdx.x & 3;
  const long cbase = (long)ch * (LLTOT * 2);
  const char* Ag = (const char*)a_t + cbase + (long)(ti * 128) * 1024;
  const char* Bg = (const char*)b_t + cbase + (long)(tj * 128) * 1024;
  const int wr = w >> 1, wc = w & 1;
  const int mn = lane & 15, q4 = lane >> 4;

  f32x4 acc[4][4];
#pragma unroll
  for (int i = 0; i < 4; ++i)
#pragma unroll
    for (int j = 0; j < 4; ++j) acc[i][j] = (f32x4){0.f, 0.f, 0.f, 0.f};

#pragma unroll 1
  for (int kst = 0; kst < 8; ++kst) {
    int4 ra[4], rb[4];
#pragma unroll
    for (int it = 0; it < 4; ++it) {
      int chunk = it * 256 + t;
      int row = chunk >> 3, cc = chunk & 7;
      ra[it] = *(const int4*)(Ag + (long)row * 1024 + kst * 128 + cc * 16);
      rb[it] = *(const int4*)(Bg + (long)row * 1024 + kst * 128 + cc * 16);
    }
    __syncthreads();   // previous stage's compute done before overwrite
#pragma unroll
    for (int it = 0; it < 4; ++it) {
      int chunk = it * 256 + t;
      int row = chunk >> 3, cc = chunk & 7;
      int sc = cc ^ (row & 7);
      *(int4*)(&Abuf[row * 128 + sc * 16]) = ra[it];
      *(int4*)(&Bbuf[row * 128 + sc * 16]) = rb[it];
    }
    __syncthreads();
#pragma unroll
    for (int kk = 0; kk < 2; ++kk) {
      bf16x8 af[4], bfv[4];
#pragma unroll
      for (int mt = 0; mt < 4; ++mt) {
        int row = wr * 64 + mt * 16 + mn;
        int chunk = kk * 4 + q4;
        af[mt] = *(const bf16x8*)(&Abuf[row * 128 + (chunk ^ (row & 7)) * 16]);
      }
#pragma unroll
      for (int nt = 0; nt < 4; ++nt) {
        int row = wc * 64 + nt * 16 + mn;
        int chunk = kk * 4 + q4;
        bfv[nt] = *(const bf16x8*)(&Bbuf[row * 128 + (chunk ^ (row & 7)) * 16]);
      }
#pragma unroll
      for (int mt = 0; mt < 4; ++mt)
#pragma unroll
        for (int nt = 0; nt < 4; ++nt)
          acc[mt][nt] = __builtin_amdgcn_mfma_f32_16x16x32_bf16(af[mt], bfv[nt], acc[mt][nt], 0, 0, 0);
    }
  }
  __syncthreads();
  // epilogue: per-wave LDS bounce (rows padded to 144B), coalesced bf16 store
  unsigned char* eb = shm + w * 9216;
#pragma unroll
  for (int mt = 0; mt < 4; ++mt)
#pragma unroll
    for (int nt = 0; nt < 4; ++nt)
#pragma unroll
      for (int r = 0; r < 4; ++r) {
        int rl = mt * 16 + q4 * 4 + r;
        int cl = nt * 16 + mn;
        *(unsigned short*)(&eb[rl * 144 + cl * 2]) = f2bf(acc[mt][nt][r]);
      }
  char* Mg = (char*)m_t + cbase + (long)(ti * 128 + wr * 64) * 1024 + (tj * 128 + wc * 64) * 2;
#pragma unroll
  for (int it = 0; it < 8; ++it) {
    int rl = it * 8 + (lane >> 3), cc = lane & 7;
    *(int4*)(Mg + (long)rl * 1024 + cc * 16) = *(const int4*)(&eb[rl * 144 + cc * 16]);
  }
}

// ---------------------------------------------------------------------------
// K4: per 64-row tile: LN(m) over c, m_ln @ Wpo, * g * mask -> dz fp32
// ---------------------------------------------------------------------------
__global__ __launch_bounds__(256) void k_out(const unsigned short* __restrict__ m_t,
                                             const unsigned short* __restrict__ gbuf,
                                             const unsigned short* __restrict__ Wt,
                                             const int* __restrict__ maskp,
                                             const float* __restrict__ lnw,
                                             const float* __restrict__ lnb,
                                             float* __restrict__ out) {
  __shared__ unsigned char mln[64 * 272];   // [row][c] bf16, padded rows
  __shared__ float obuf[64 * 132];          // [row][c] fp32, padded rows
  __shared__ float lw[128], lb[128], mk[64];
  const int t = threadIdx.x;
  const long r0 = (long)blockIdx.x * 64;

  // stage + transpose m tile: m_t[c][r0+..] -> mln[row][c]
#pragma unroll
  for (int it = 0; it < 4; ++it) {
    int chunk = it * 256 + t;
    int c = chunk >> 3, cc = chunk & 7;
    int4 rv = *(const int4*)((const char*)m_t + (long)c * 524288 + r0 * 2 + cc * 16);
    const unsigned short* rp = (const unsigned short*)&rv;
#pragma unroll
    for (int e = 0; e < 8; ++e)
      *(unsigned short*)(&mln[(cc * 8 + e) * 272 + c * 2]) = rp[e];
  }
  if (t < 128) { lw[t] = lnw[t]; lb[t] = lnb[t]; }
  if (t < 64) mk[t] = (float)maskp[r0 + t];
  __syncthreads();

  {  // LayerNorm over c: 4 threads per row; write m_ln back in place (bf16)
    int row = t >> 2, part = t & 3;
    float xv[32];
    float s = 0.f, q = 0.f;
#pragma unroll
    for (int j = 0; j < 16; ++j) {
      unsigned u = *(const unsigned*)(&mln[row * 272 + part * 64 + j * 4]);
      float x0 = bf2f((unsigned short)(u & 0xffff));
      float x1 = bf2f((unsigned short)(u >> 16));
      xv[2 * j] = x0; xv[2 * j + 1] = x1;
      s += x0 + x1; q += x0 * x0 + x1 * x1;
    }
    s += __shfl_xor(s, 1); q += __shfl_xor(q, 1);
    s += __shfl_xor(s, 2); q += __shfl_xor(q, 2);
    float mu = s * (1.f / 128.f);
    float var = q * (1.f / 128.f) - mu * mu;
    float rs = rsqrtf(var + EPSV);
#pragma unroll
    for (int j = 0; j < 16; ++j) {
      int c = part * 32 + 2 * j;
      unsigned short h0 = f2bf((xv[2 * j] - mu) * rs * lw[c] + lb[c]);
      unsigned short h1 = f2bf((xv[2 * j + 1] - mu) * rs * lw[c + 1] + lb[c + 1]);
      *(unsigned*)(&mln[row * 272 + c * 2]) = (unsigned)h0 | ((unsigned)h1 << 16);
    }
  }
  __syncthreads();

  // GEMM: m_ln @ Wpo -> obuf (raw acc)
  const int w = t >> 6, lane = t & 63;
  const int mn = lane & 15, q4 = lane >> 4;
  bf16x8 afr[4];
#pragma unroll
  for (int kk = 0; kk < 4; ++kk)
    afr[kk] = *(const bf16x8*)(&mln[(w * 16 + mn) * 272 + kk * 64 + q4 * 16]);
  const unsigned short* Wp = Wt + 5 * 16384;
#pragma unroll 1
  for (int nt = 0; nt < 8; ++nt) {
    f32x4 acc = {0.f, 0.f, 0.f, 0.f};
#pragma unroll
    for (int kk = 0; kk < 4; ++kk) {
      bf16x8 bfr = *(const bf16x8*)(Wp + (nt * 16 + mn) * 128 + kk * 32 + q4 * 8);
      acc = __builtin_amdgcn_mfma_f32_16x16x32_bf16(afr[kk], bfr, acc, 0, 0, 0);
    }
    const int cl = nt * 16 + mn;
#pragma unroll
    for (int r = 0; r < 4; ++r)
      obuf[(w * 16 + q4 * 4 + r) * 132 + cl] = acc[r];
  }
  __syncthreads();

  // out = obuf * g * mask (coalesced; g read as bf16x4 chunks)
#pragma unroll
  for (int it = 0; it < 8; ++it) {
    int chunk = it * 256 + t;
    int row = chunk >> 5, cc = chunk & 31;
    float4 v = *(const float4*)(&obuf[row * 132 + cc * 4]);
    uint2 gp = *(const uint2*)((const char*)gbuf + (r0 + row) * 256 + cc * 8);
    float mval = mk[row];
    v.x *= bf2f((unsigned short)(gp.x & 0xffff)) * mval;
    v.y *= bf2f((unsigned short)(gp.x >> 16)) * mval;
    v.z *= bf2f((unsigned short)(gp.y & 0xffff)) * mval;
    v.w *= bf2f((unsigned short)(gp.y >> 16)) * mval;
    *(float4*)(out + (r0 + row) * 128 + cc * 4) = v;
  }
}

// ---------------------------------------------------------------------------
extern "C" void kernel_launch(void* const* d_in, const int* in_sizes, int n_in,
                              void* d_out, int out_size, void* d_ws, size_t ws_size,
                              hipStream_t stream) {
  const float* z    = (const float*)d_in[0];
  const int* maskp  = (const int*)d_in[1];
  const float* lniw = (const float*)d_in[2];
  const float* lnib = (const float*)d_in[3];
  const float* lnow = (const float*)d_in[4];
  const float* lnob = (const float*)d_in[5];
  const float* Wpa  = (const float*)d_in[6];
  const float* Wga  = (const float*)d_in[7];
  const float* Wpb  = (const float*)d_in[8];
  const float* Wgb  = (const float*)d_in[9];
  const float* Wgo  = (const float*)d_in[10];
  const float* Wpo  = (const float*)d_in[11];
  float* out = (float*)d_out;

  char* ws = (char*)d_ws;
  unsigned short* a_t = (unsigned short*)(ws);                 // bf16 [128][262144]
  unsigned short* b_t = (unsigned short*)(ws + 67108864);      // bf16 [128][262144]
  unsigned short* g   = (unsigned short*)(ws + 134217728);     // bf16 [262144][128]
  unsigned short* zm  = (unsigned short*)(ws + 201326592);     // zln then m_t (67 MB)
  unsigned short* Wt  = (unsigned short*)(ws + 268435456);     // 6 x [128][128] bf16

  k_prep<<<384, 256, 0, stream>>>(Wpa, Wga, Wpb, Wgb, Wgo, Wpo, Wt);
  k_ln_in<<<65536, 256, 0, stream>>>(z, lniw, lnib, zm);
  k_proj<<<2048, 256, 0, stream>>>(zm, Wt, maskp, a_t, b_t, g);
  dim3 g3(16, 128);
  k_einsum<<<g3, 256, 0, stream>>>(a_t, b_t, zm);   // zm now holds m_t
  k_out<<<4096, 256, 0, stream>>>(zm, g, Wt, maskp, lnow, lnob, out);
}

// Round 2
// 692.732 us; speedup vs baseline: 1.0512x; 1.0512x over previous
//
#include <hip/hip_runtime.h>
#include <stdint.h>

#define LDIM 512
#define LLTOT 262144            // 512*512
#define EPSV 1e-5f

typedef short bf16x8 __attribute__((ext_vector_type(8)));
typedef float f32x4 __attribute__((ext_vector_type(4)));

__device__ __forceinline__ unsigned short f2bf(float f) {
  union { float f; unsigned u; } v; v.f = f;
  unsigned r = v.u + 0x7FFFu + ((v.u >> 16) & 1u);   // RNE
  return (unsigned short)(r >> 16);
}
__device__ __forceinline__ float bf2f(unsigned short h) {
  union { unsigned u; float f; } v; v.u = ((unsigned)h) << 16;
  return v.f;
}
__device__ __forceinline__ float sigm(float x) { return 1.0f / (1.0f + __expf(-x)); }

// ---------------------------------------------------------------------------
// K0: weights fp32 [c][o] -> bf16 transposed [o][c].  Order: ga,pa,gb,pb,go,po
// ---------------------------------------------------------------------------
__global__ void k_prep(const float* __restrict__ Wpa, const float* __restrict__ Wga,
                       const float* __restrict__ Wpb, const float* __restrict__ Wgb,
                       const float* __restrict__ Wgo, const float* __restrict__ Wpo,
                       unsigned short* __restrict__ Wt) {
  int t = blockIdx.x * blockDim.x + threadIdx.x;     // 0..98303
  int mat = t >> 14;
  int rem = t & 16383;
  int o = rem >> 7;
  int c = rem & 127;
  const float* src;
  switch (mat) {
    case 0: src = Wga; break;
    case 1: src = Wpa; break;
    case 2: src = Wgb; break;
    case 3: src = Wpb; break;
    case 4: src = Wgo; break;
    default: src = Wpo; break;
  }
  Wt[mat * 16384 + o * 128 + c] = f2bf(src[c * 128 + o]);
}

// ---------------------------------------------------------------------------
// K1 (fused LN + projections).  Per block: 128 rows.
//  z -> LN (fp32) -> zbuf bf16; then
//  a = sigmoid(zln@Wga)*(zln@Wpa)*mask  -> a_t[c][row]  (channel-major, bf16)
//  b = ... -> b_t[c][row];  g = sigmoid(zln@Wgo) -> g[row][c] (bf16)
// ---------------------------------------------------------------------------
__global__ __launch_bounds__(256) void k_proj(const float* __restrict__ z,
                                              const float* __restrict__ lnw,
                                              const float* __restrict__ lnb,
                                              const unsigned short* __restrict__ Wt,
                                              const int* __restrict__ maskp,
                                              unsigned short* __restrict__ a_t,
                                              unsigned short* __restrict__ b_t,
                                              unsigned short* __restrict__ gout) {
  __shared__ unsigned char zbuf[128 * 272];   // rows padded 256->272B (bank spread)
  __shared__ float maskf[128];
  const int t = threadIdx.x;
  const long r0 = (long)blockIdx.x * 128;
  const int w = t >> 6, lane = t & 63;

  if (t < 128) maskf[t] = (float)maskp[r0 + t];

  // fused input LayerNorm: each wave handles 32 rows; lane holds 2 channels
  const float lw0 = lnw[2 * lane], lw1 = lnw[2 * lane + 1];
  const float lb0 = lnb[2 * lane], lb1 = lnb[2 * lane + 1];
#pragma unroll 2
  for (int rr = 0; rr < 32; rr += 4) {
    float2 v[4];
#pragma unroll
    for (int i = 0; i < 4; ++i)
      v[i] = ((const float2*)(z + (r0 + w * 32 + rr + i) * 128))[lane];
#pragma unroll
    for (int i = 0; i < 4; ++i) {
      float s = v[i].x + v[i].y, q = v[i].x * v[i].x + v[i].y * v[i].y;
#pragma unroll
      for (int off = 32; off; off >>= 1) { s += __shfl_xor(s, off); q += __shfl_xor(q, off); }
      float mu = s * (1.0f / 128.0f);
      float rs = rsqrtf(q * (1.0f / 128.0f) - mu * mu + EPSV);
      ushort2 o;
      o.x = f2bf((v[i].x - mu) * rs * lw0 + lb0);
      o.y = f2bf((v[i].y - mu) * rs * lw1 + lb1);
      ((ushort2*)&zbuf[(w * 32 + rr + i) * 272])[lane] = o;
    }
  }
  __syncthreads();

  const int mn = lane & 15, q4 = lane >> 4;

  // whole A-tile of this wave (32 rows x 128 k) in registers
  bf16x8 afr[2][4];
#pragma unroll
  for (int mt = 0; mt < 2; ++mt)
#pragma unroll
    for (int kk = 0; kk < 4; ++kk)
      afr[mt][kk] = *(const bf16x8*)(&zbuf[(w * 32 + mt * 16 + mn) * 272 + kk * 64 + q4 * 16]);
  __syncthreads();   // zbuf reusable (g bounce below)

#pragma unroll 1
  for (int p = 0; p < 2; ++p) {
    const unsigned short* Wg = Wt + (p * 2) * 16384;
    const unsigned short* Wp = Wt + (p * 2 + 1) * 16384;
    unsigned short* dst = p ? b_t : a_t;
#pragma unroll 1
    for (int nt = 0; nt < 8; ++nt) {
      f32x4 aG0 = {0.f,0.f,0.f,0.f}, aG1 = {0.f,0.f,0.f,0.f};
      f32x4 aP0 = {0.f,0.f,0.f,0.f}, aP1 = {0.f,0.f,0.f,0.f};
#pragma unroll
      for (int kk = 0; kk < 4; ++kk) {
        bf16x8 bg = *(const bf16x8*)(Wg + (nt * 16 + mn) * 128 + kk * 32 + q4 * 8);
        bf16x8 bp = *(const bf16x8*)(Wp + (nt * 16 + mn) * 128 + kk * 32 + q4 * 8);
        aG0 = __builtin_amdgcn_mfma_f32_16x16x32_bf16(afr[0][kk], bg, aG0, 0, 0, 0);
        aG1 = __builtin_amdgcn_mfma_f32_16x16x32_bf16(afr[1][kk], bg, aG1, 0, 0, 0);
        aP0 = __builtin_amdgcn_mfma_f32_16x16x32_bf16(afr[0][kk], bp, aP0, 0, 0, 0);
        aP1 = __builtin_amdgcn_mfma_f32_16x16x32_bf16(afr[1][kk], bp, aP1, 0, 0, 0);
      }
      const int c = nt * 16 + mn;
#pragma unroll
      for (int mt = 0; mt < 2; ++mt) {
        const f32x4 vG = mt ? aG1 : aG0;
        const f32x4 vP = mt ? aP1 : aP0;
        const int rowb = w * 32 + mt * 16 + q4 * 4;
        unsigned short hv[4];
#pragma unroll
        for (int r = 0; r < 4; ++r)
          hv[r] = f2bf(sigm(vG[r]) * vP[r] * maskf[rowb + r]);
        uint2 pk;
        pk.x = (unsigned)hv[0] | ((unsigned)hv[1] << 16);
        pk.y = (unsigned)hv[2] | ((unsigned)hv[3] << 16);
        *(uint2*)(dst + (long)c * LLTOT + r0 + rowb) = pk;   // 4 contig rows of a_t[c]
      }
    }
  }

  {  // g = sigmoid(zln @ Wgo), bounce via zbuf for coalesced [row][c] store
    const unsigned short* Wg = Wt + 4 * 16384;
#pragma unroll 1
    for (int nt = 0; nt < 8; ++nt) {
      f32x4 aG0 = {0.f,0.f,0.f,0.f}, aG1 = {0.f,0.f,0.f,0.f};
#pragma unroll
      for (int kk = 0; kk < 4; ++kk) {
        bf16x8 bg = *(const bf16x8*)(Wg + (nt * 16 + mn) * 128 + kk * 32 + q4 * 8);
        aG0 = __builtin_amdgcn_mfma_f32_16x16x32_bf16(afr[0][kk], bg, aG0, 0, 0, 0);
        aG1 = __builtin_amdgcn_mfma_f32_16x16x32_bf16(afr[1][kk], bg, aG1, 0, 0, 0);
      }
      const int c = nt * 16 + mn;
#pragma unroll
      for (int mt = 0; mt < 2; ++mt) {
        const f32x4 vG = mt ? aG1 : aG0;
        const int rowb = w * 32 + mt * 16 + q4 * 4;
#pragma unroll
        for (int r = 0; r < 4; ++r)
          *(unsigned short*)(&zbuf[(rowb + r) * 272 + c * 2]) = f2bf(sigm(vG[r]));
      }
    }
  }
  __syncthreads();
  {
    char* gdst = (char*)gout + r0 * 256;
#pragma unroll
    for (int it = 0; it < 8; ++it) {
      int chunk = it * 256 + t;
      int row = chunk >> 4, cc = chunk & 15;
      *(int4*)(gdst + row * 256 + cc * 16) = *(const int4*)(&zbuf[row * 272 + cc * 16]);
    }
  }
}

// ---------------------------------------------------------------------------
// K3: per-channel GEMM  m_c = a_c @ b_c^T  (both [512][512] bf16 row-major,
// k-contiguous).  128x128 tile per block, BK=64, XOR-swizzled LDS.
// XCD-affinity: bid&7 selects XCD (round-robin dispatch); all 16 tiles of a
// channel land on ONE XCD so the channel's 1 MB working set lives in its L2.
// ---------------------------------------------------------------------------
__global__ __launch_bounds__(256) void k_einsum(const unsigned short* __restrict__ a_t,
                                                const unsigned short* __restrict__ b_t,
                                                unsigned short* __restrict__ m_t) {
  __shared__ unsigned char shm[36864];   // A 16K + B 16K; epilogue: 4 x 9216B
  unsigned char* Abuf = shm;
  unsigned char* Bbuf = shm + 16384;
  const int t = threadIdx.x;
  const int w = t >> 6, lane = t & 63;
  const int bid = blockIdx.x;
  const int xcd = bid & 7;               // assumes round-robin bid%8 -> XCD
  const int j = bid >> 3;                // 0..255 within XCD
  const int ch = xcd * 16 + (j >> 4);    // 16 channels per XCD
  const int tile = j & 15;               // 16 tiles per channel, consecutive
  const int ti = tile >> 2, tj = tile & 3;
  const long cbase = (long)ch * (LLTOT * 2);
  const char* Ag = (const char*)a_t + cbase + (long)(ti * 128) * 1024;
  const char* Bg = (const char*)b_t + cbase + (long)(tj * 128) * 1024;
  const int wr = w >> 1, wc = w & 1;
  const int mn = lane & 15, q4 = lane >> 4;

  f32x4 acc[4][4];
#pragma unroll
  for (int i = 0; i < 4; ++i)
#pragma unroll
    for (int jj = 0; jj < 4; ++jj) acc[i][jj] = (f32x4){0.f, 0.f, 0.f, 0.f};

#pragma unroll 1
  for (int kst = 0; kst < 8; ++kst) {
    int4 ra[4], rb[4];
#pragma unroll
    for (int it = 0; it < 4; ++it) {
      int chunk = it * 256 + t;
      int row = chunk >> 3, cc = chunk & 7;
      ra[it] = *(const int4*)(Ag + (long)row * 1024 + kst * 128 + cc * 16);
      rb[it] = *(const int4*)(Bg + (long)row * 1024 + kst * 128 + cc * 16);
    }
    __syncthreads();   // previous stage's compute done before overwrite
#pragma unroll
    for (int it = 0; it < 4; ++it) {
      int chunk = it * 256 + t;
      int row = chunk >> 3, cc = chunk & 7;
      int sc = cc ^ (row & 7);
      *(int4*)(&Abuf[row * 128 + sc * 16]) = ra[it];
      *(int4*)(&Bbuf[row * 128 + sc * 16]) = rb[it];
    }
    __syncthreads();
#pragma unroll
    for (int kk = 0; kk < 2; ++kk) {
      bf16x8 af[4], bfv[4];
#pragma unroll
      for (int mt = 0; mt < 4; ++mt) {
        int row = wr * 64 + mt * 16 + mn;
        int chunk = kk * 4 + q4;
        af[mt] = *(const bf16x8*)(&Abuf[row * 128 + (chunk ^ (row & 7)) * 16]);
      }
#pragma unroll
      for (int nt = 0; nt < 4; ++nt) {
        int row = wc * 64 + nt * 16 + mn;
        int chunk = kk * 4 + q4;
        bfv[nt] = *(const bf16x8*)(&Bbuf[row * 128 + (chunk ^ (row & 7)) * 16]);
      }
#pragma unroll
      for (int mt = 0; mt < 4; ++mt)
#pragma unroll
        for (int nt = 0; nt < 4; ++nt)
          acc[mt][nt] = __builtin_amdgcn_mfma_f32_16x16x32_bf16(af[mt], bfv[nt], acc[mt][nt], 0, 0, 0);
    }
  }
  __syncthreads();
  // epilogue: per-wave LDS bounce (rows padded to 144B), coalesced bf16 store
  unsigned char* eb = shm + w * 9216;
#pragma unroll
  for (int mt = 0; mt < 4; ++mt)
#pragma unroll
    for (int nt = 0; nt < 4; ++nt)
#pragma unroll
      for (int r = 0; r < 4; ++r) {
        int rl = mt * 16 + q4 * 4 + r;
        int cl = nt * 16 + mn;
        *(unsigned short*)(&eb[rl * 144 + cl * 2]) = f2bf(acc[mt][nt][r]);
      }
  char* Mg = (char*)m_t + cbase + (long)(ti * 128 + wr * 64) * 1024 + (tj * 128 + wc * 64) * 2;
#pragma unroll
  for (int it = 0; it < 8; ++it) {
    int rl = it * 8 + (lane >> 3), cc = lane & 7;
    *(int4*)(Mg + (long)rl * 1024 + cc * 16) = *(const int4*)(&eb[rl * 144 + cc * 16]);
  }
}

// ---------------------------------------------------------------------------
// K4: per 64-row tile: LN(m) over c, m_ln @ Wpo, * g * mask -> dz fp32
// ---------------------------------------------------------------------------
__global__ __launch_bounds__(256) void k_out(const unsigned short* __restrict__ m_t,
                                             const unsigned short* __restrict__ gbuf,
                                             const unsigned short* __restrict__ Wt,
                                             const int* __restrict__ maskp,
                                             const float* __restrict__ lnw,
                                             const float* __restrict__ lnb,
                                             float* __restrict__ out) {
  __shared__ unsigned char mln[64 * 272];   // [row][c] bf16, padded rows
  __shared__ float obuf[64 * 132];          // [row][c] fp32, padded rows
  __shared__ float lw[128], lb[128], mk[64];
  const int t = threadIdx.x;
  const long r0 = (long)blockIdx.x * 64;

  // stage + transpose m tile: m_t[c][r0+..] -> mln[row][c]
#pragma unroll
  for (int it = 0; it < 4; ++it) {
    int chunk = it * 256 + t;
    int c = chunk >> 3, cc = chunk & 7;
    int4 rv = *(const int4*)((const char*)m_t + (long)c * 524288 + r0 * 2 + cc * 16);
    const unsigned short* rp = (const unsigned short*)&rv;
#pragma unroll
    for (int e = 0; e < 8; ++e)
      *(unsigned short*)(&mln[(cc * 8 + e) * 272 + c * 2]) = rp[e];
  }
  if (t < 128) { lw[t] = lnw[t]; lb[t] = lnb[t]; }
  if (t < 64) mk[t] = (float)maskp[r0 + t];
  __syncthreads();

  {  // LayerNorm over c: 4 threads per row; write m_ln back in place (bf16)
    int row = t >> 2, part = t & 3;
    float xv[32];
    float s = 0.f, q = 0.f;
#pragma unroll
    for (int jj = 0; jj < 16; ++jj) {
      unsigned u = *(const unsigned*)(&mln[row * 272 + part * 64 + jj * 4]);
      float x0 = bf2f((unsigned short)(u & 0xffff));
      float x1 = bf2f((unsigned short)(u >> 16));
      xv[2 * jj] = x0; xv[2 * jj + 1] = x1;
      s += x0 + x1; q += x0 * x0 + x1 * x1;
    }
    s += __shfl_xor(s, 1); q += __shfl_xor(q, 1);
    s += __shfl_xor(s, 2); q += __shfl_xor(q, 2);
    float mu = s * (1.f / 128.f);
    float var = q * (1.f / 128.f) - mu * mu;
    float rs = rsqrtf(var + EPSV);
#pragma unroll
    for (int jj = 0; jj < 16; ++jj) {
      int c = part * 32 + 2 * jj;
      unsigned short h0 = f2bf((xv[2 * jj] - mu) * rs * lw[c] + lb[c]);
      unsigned short h1 = f2bf((xv[2 * jj + 1] - mu) * rs * lw[c + 1] + lb[c + 1]);
      *(unsigned*)(&mln[row * 272 + c * 2]) = (unsigned)h0 | ((unsigned)h1 << 16);
    }
  }
  __syncthreads();

  // GEMM: m_ln @ Wpo -> obuf (raw acc)
  const int w = t >> 6, lane = t & 63;
  const int mn = lane & 15, q4 = lane >> 4;
  bf16x8 afr[4];
#pragma unroll
  for (int kk = 0; kk < 4; ++kk)
    afr[kk] = *(const bf16x8*)(&mln[(w * 16 + mn) * 272 + kk * 64 + q4 * 16]);
  const unsigned short* Wp = Wt + 5 * 16384;
#pragma unroll 1
  for (int nt = 0; nt < 8; ++nt) {
    f32x4 acc = {0.f, 0.f, 0.f, 0.f};
#pragma unroll
    for (int kk = 0; kk < 4; ++kk) {
      bf16x8 bfr = *(const bf16x8*)(Wp + (nt * 16 + mn) * 128 + kk * 32 + q4 * 8);
      acc = __builtin_amdgcn_mfma_f32_16x16x32_bf16(afr[kk], bfr, acc, 0, 0, 0);
    }
    const int cl = nt * 16 + mn;
#pragma unroll
    for (int r = 0; r < 4; ++r)
      obuf[(w * 16 + q4 * 4 + r) * 132 + cl] = acc[r];
  }
  __syncthreads();

  // out = obuf * g * mask (coalesced; g read as bf16x4 chunks)
#pragma unroll
  for (int it = 0; it < 8; ++it) {
    int chunk = it * 256 + t;
    int row = chunk >> 5, cc = chunk & 31;
    float4 v = *(const float4*)(&obuf[row * 132 + cc * 4]);
    uint2 gp = *(const uint2*)((const char*)gbuf + (r0 + row) * 256 + cc * 8);
    float mval = mk[row];
    v.x *= bf2f((unsigned short)(gp.x & 0xffff)) * mval;
    v.y *= bf2f((unsigned short)(gp.x >> 16)) * mval;
    v.z *= bf2f((unsigned short)(gp.y & 0xffff)) * mval;
    v.w *= bf2f((unsigned short)(gp.y >> 16)) * mval;
    *(float4*)(out + (r0 + row) * 128 + cc * 4) = v;
  }
}

// ---------------------------------------------------------------------------
extern "C" void kernel_launch(void* const* d_in, const int* in_sizes, int n_in,
                              void* d_out, int out_size, void* d_ws, size_t ws_size,
                              hipStream_t stream) {
  const float* z    = (const float*)d_in[0];
  const int* maskp  = (const int*)d_in[1];
  const float* lniw = (const float*)d_in[2];
  const float* lnib = (const float*)d_in[3];
  const float* lnow = (const float*)d_in[4];
  const float* lnob = (const float*)d_in[5];
  const float* Wpa  = (const float*)d_in[6];
  const float* Wga  = (const float*)d_in[7];
  const float* Wpb  = (const float*)d_in[8];
  const float* Wgb  = (const float*)d_in[9];
  const float* Wgo  = (const float*)d_in[10];
  const float* Wpo  = (const float*)d_in[11];
  float* out = (float*)d_out;

  char* ws = (char*)d_ws;
  unsigned short* a_t = (unsigned short*)(ws);                 // bf16 [128][262144]
  unsigned short* b_t = (unsigned short*)(ws + 67108864);      // bf16 [128][262144]
  unsigned short* g   = (unsigned short*)(ws + 134217728);     // bf16 [262144][128]
  unsigned short* m_t = (unsigned short*)(ws + 201326592);     // bf16 [128][262144]
  unsigned short* Wt  = (unsigned short*)(ws + 268435456);     // 6 x [128][128] bf16

  k_prep<<<384, 256, 0, stream>>>(Wpa, Wga, Wpb, Wgb, Wgo, Wpo, Wt);
  k_proj<<<2048, 256, 0, stream>>>(z, lniw, lnib, Wt, maskp, a_t, b_t, g);
  k_einsum<<<2048, 256, 0, stream>>>(a_t, b_t, m_t);
  k_out<<<4096, 256, 0, stream>>>(m_t, g, Wt, maskp, lnow, lnob, out);
}

// Round 3
// 657.217 us; speedup vs baseline: 1.1080x; 1.0540x over previous
//
#include <hip/hip_runtime.h>
#include <stdint.h>

#define LDIM 512
#define LLTOT 262144            // 512*512
#define EPSV 1e-5f

typedef short bf16x8 __attribute__((ext_vector_type(8)));
typedef float f32x4 __attribute__((ext_vector_type(4)));

__device__ __forceinline__ unsigned short f2bf(float f) {
  union { float f; unsigned u; } v; v.f = f;
  unsigned r = v.u + 0x7FFFu + ((v.u >> 16) & 1u);   // RNE
  return (unsigned short)(r >> 16);
}
__device__ __forceinline__ float bf2f(unsigned short h) {
  union { unsigned u; float f; } v; v.u = ((unsigned)h) << 16;
  return v.f;
}
__device__ __forceinline__ float sigm(float x) { return 1.0f / (1.0f + __expf(-x)); }

// ---------------------------------------------------------------------------
// K0: weights fp32 [c][o] -> bf16 transposed [o][c].  Order: ga,pa,gb,pb,go,po
// ---------------------------------------------------------------------------
__global__ void k_prep(const float* __restrict__ Wpa, const float* __restrict__ Wga,
                       const float* __restrict__ Wpb, const float* __restrict__ Wgb,
                       const float* __restrict__ Wgo, const float* __restrict__ Wpo,
                       unsigned short* __restrict__ Wt) {
  int t = blockIdx.x * blockDim.x + threadIdx.x;     // 0..98303
  int mat = t >> 14;
  int rem = t & 16383;
  int o = rem >> 7;
  int c = rem & 127;
  const float* src;
  switch (mat) {
    case 0: src = Wga; break;
    case 1: src = Wpa; break;
    case 2: src = Wgb; break;
    case 3: src = Wpb; break;
    case 4: src = Wgo; break;
    default: src = Wpo; break;
  }
  Wt[mat * 16384 + o * 128 + c] = f2bf(src[c * 128 + o]);
}

// ---------------------------------------------------------------------------
// K1 (fused LN + projections), weights-resident version.
// Per block: 128 rows.  Wave w owns output channels [32w, 32w+32).
// Weight fragments loaded ONCE per phase into VGPRs; rows streamed from LDS.
// ---------------------------------------------------------------------------
__global__ __launch_bounds__(256) void k_proj(const float* __restrict__ z,
                                              const float* __restrict__ lnw,
                                              const float* __restrict__ lnb,
                                              const unsigned short* __restrict__ Wt,
                                              const int* __restrict__ maskp,
                                              unsigned short* __restrict__ a_t,
                                              unsigned short* __restrict__ b_t,
                                              unsigned short* __restrict__ gout) {
  __shared__ unsigned char zbuf[128 * 272];   // rows padded 256->272B
  __shared__ float maskf[128];
  const int t = threadIdx.x;
  const long r0 = (long)blockIdx.x * 128;
  const int w = t >> 6, lane = t & 63;
  const int mn = lane & 15, q4 = lane >> 4;

  if (t < 128) maskf[t] = (float)maskp[r0 + t];

  // fused input LayerNorm: each wave handles 32 rows; lane holds 2 channels
  const float lw0 = lnw[2 * lane], lw1 = lnw[2 * lane + 1];
  const float lb0 = lnb[2 * lane], lb1 = lnb[2 * lane + 1];
#pragma unroll 2
  for (int rr = 0; rr < 32; rr += 4) {
    float2 v[4];
#pragma unroll
    for (int i = 0; i < 4; ++i)
      v[i] = ((const float2*)(z + (r0 + w * 32 + rr + i) * 128))[lane];
#pragma unroll
    for (int i = 0; i < 4; ++i) {
      float s = v[i].x + v[i].y, q = v[i].x * v[i].x + v[i].y * v[i].y;
#pragma unroll
      for (int off = 32; off; off >>= 1) { s += __shfl_xor(s, off); q += __shfl_xor(q, off); }
      float mu = s * (1.0f / 128.0f);
      float rs = rsqrtf(q * (1.0f / 128.0f) - mu * mu + EPSV);
      ushort2 o;
      o.x = f2bf((v[i].x - mu) * rs * lw0 + lb0);
      o.y = f2bf((v[i].y - mu) * rs * lw1 + lb1);
      ((ushort2*)&zbuf[(w * 32 + rr + i) * 272])[lane] = o;
    }
  }
  __syncthreads();

  // phases p=0 (a), p=1 (b): gate+proj weights resident in VGPRs
#pragma unroll 1
  for (int p = 0; p < 2; ++p) {
    const unsigned short* Wg = Wt + (p * 2) * 16384;
    const unsigned short* Wp = Wt + (p * 2 + 1) * 16384;
    unsigned short* dst = p ? b_t : a_t;
    bf16x8 wg[2][4], wp[2][4];
#pragma unroll
    for (int ntl = 0; ntl < 2; ++ntl)
#pragma unroll
      for (int kk = 0; kk < 4; ++kk) {
        const int o = (w * 2 + ntl) * 16 + mn;
        wg[ntl][kk] = *(const bf16x8*)(Wg + o * 128 + kk * 32 + q4 * 8);
        wp[ntl][kk] = *(const bf16x8*)(Wp + o * 128 + kk * 32 + q4 * 8);
      }
#pragma unroll 1
    for (int rg = 0; rg < 8; ++rg) {
      bf16x8 afr[4];
#pragma unroll
      for (int kk = 0; kk < 4; ++kk)
        afr[kk] = *(const bf16x8*)(&zbuf[(rg * 16 + mn) * 272 + kk * 64 + q4 * 16]);
      f32x4 aG[2] = {{0.f,0.f,0.f,0.f},{0.f,0.f,0.f,0.f}};
      f32x4 aP[2] = {{0.f,0.f,0.f,0.f},{0.f,0.f,0.f,0.f}};
#pragma unroll
      for (int kk = 0; kk < 4; ++kk)
#pragma unroll
        for (int ntl = 0; ntl < 2; ++ntl) {
          aG[ntl] = __builtin_amdgcn_mfma_f32_16x16x32_bf16(afr[kk], wg[ntl][kk], aG[ntl], 0, 0, 0);
          aP[ntl] = __builtin_amdgcn_mfma_f32_16x16x32_bf16(afr[kk], wp[ntl][kk], aP[ntl], 0, 0, 0);
        }
      const int rowb = rg * 16 + q4 * 4;
#pragma unroll
      for (int ntl = 0; ntl < 2; ++ntl) {
        const int c = (w * 2 + ntl) * 16 + mn;
        unsigned short hv[4];
#pragma unroll
        for (int r = 0; r < 4; ++r)
          hv[r] = f2bf(sigm(aG[ntl][r]) * aP[ntl][r] * maskf[rowb + r]);
        uint2 pk;
        pk.x = (unsigned)hv[0] | ((unsigned)hv[1] << 16);
        pk.y = (unsigned)hv[2] | ((unsigned)hv[3] << 16);
        *(uint2*)(dst + (long)c * LLTOT + r0 + rowb) = pk;
      }
    }
  }

  {  // g phase: g = sigmoid(zln @ Wgo) -> gout[row][c] (direct 2B stores, L2 merges)
    const unsigned short* Wgp = Wt + 4 * 16384;
    bf16x8 wg[2][4];
#pragma unroll
    for (int ntl = 0; ntl < 2; ++ntl)
#pragma unroll
      for (int kk = 0; kk < 4; ++kk)
        wg[ntl][kk] = *(const bf16x8*)(Wgp + ((w * 2 + ntl) * 16 + mn) * 128 + kk * 32 + q4 * 8);
#pragma unroll 1
    for (int rg = 0; rg < 8; ++rg) {
      bf16x8 afr[4];
#pragma unroll
      for (int kk = 0; kk < 4; ++kk)
        afr[kk] = *(const bf16x8*)(&zbuf[(rg * 16 + mn) * 272 + kk * 64 + q4 * 16]);
      f32x4 aG[2] = {{0.f,0.f,0.f,0.f},{0.f,0.f,0.f,0.f}};
#pragma unroll
      for (int kk = 0; kk < 4; ++kk)
#pragma unroll
        for (int ntl = 0; ntl < 2; ++ntl)
          aG[ntl] = __builtin_amdgcn_mfma_f32_16x16x32_bf16(afr[kk], wg[ntl][kk], aG[ntl], 0, 0, 0);
      const int rowb = rg * 16 + q4 * 4;
#pragma unroll
      for (int ntl = 0; ntl < 2; ++ntl) {
        const int c = (w * 2 + ntl) * 16 + mn;
#pragma unroll
        for (int r = 0; r < 4; ++r)
          gout[(r0 + rowb + r) * 128 + c] = f2bf(sigm(aG[ntl][r]));
      }
    }
  }
}

// ---------------------------------------------------------------------------
// K3: per-channel GEMM  m_c = a_c @ b_c^T, 128x128 tile, BK=64, XOR-swizzled
// LDS, XCD-affinity swizzle, SOFTWARE-PIPELINED: loads for kst+1 issued before
// compute of kst so load latency overlaps MFMA (drained at next barrier).
// ---------------------------------------------------------------------------
__global__ __launch_bounds__(256) void k_einsum(const unsigned short* __restrict__ a_t,
                                                const unsigned short* __restrict__ b_t,
                                                unsigned short* __restrict__ m_t) {
  __shared__ unsigned char shm[36864];   // A 16K + B 16K; epilogue: 4 x 9216B
  unsigned char* Abuf = shm;
  unsigned char* Bbuf = shm + 16384;
  const int t = threadIdx.x;
  const int w = t >> 6, lane = t & 63;
  const int bid = blockIdx.x;
  const int xcd = bid & 7;               // round-robin bid%8 -> XCD
  const int j = bid >> 3;
  const int ch = xcd * 16 + (j >> 4);    // 16 channels per XCD
  const int tile = j & 15;
  const int ti = tile >> 2, tj = tile & 3;
  const long cbase = (long)ch * (LLTOT * 2);
  const char* Ag = (const char*)a_t + cbase + (long)(ti * 128) * 1024;
  const char* Bg = (const char*)b_t + cbase + (long)(tj * 128) * 1024;
  const int wr = w >> 1, wc = w & 1;
  const int mn = lane & 15, q4 = lane >> 4;

  f32x4 acc[4][4];
#pragma unroll
  for (int i = 0; i < 4; ++i)
#pragma unroll
    for (int jj = 0; jj < 4; ++jj) acc[i][jj] = (f32x4){0.f, 0.f, 0.f, 0.f};

  int4 ra[4], rb[4];
  auto loadk = [&](int ks) {
#pragma unroll
    for (int it = 0; it < 4; ++it) {
      int chunk = it * 256 + t;
      int row = chunk >> 3, cc = chunk & 7;
      ra[it] = *(const int4*)(Ag + (long)row * 1024 + ks * 128 + cc * 16);
      rb[it] = *(const int4*)(Bg + (long)row * 1024 + ks * 128 + cc * 16);
    }
  };
  loadk(0);

#pragma unroll 1
  for (int kst = 0; kst < 8; ++kst) {
    __syncthreads();   // previous compute done (LDS reusable); drains prefetch
#pragma unroll
    for (int it = 0; it < 4; ++it) {
      int chunk = it * 256 + t;
      int row = chunk >> 3, cc = chunk & 7;
      int sc = cc ^ (row & 7);
      *(int4*)(&Abuf[row * 128 + sc * 16]) = ra[it];
      *(int4*)(&Bbuf[row * 128 + sc * 16]) = rb[it];
    }
    __syncthreads();
    if (kst < 7) loadk(kst + 1);   // in flight across compute
#pragma unroll
    for (int kk = 0; kk < 2; ++kk) {
      bf16x8 af[4], bfv[4];
#pragma unroll
      for (int mt = 0; mt < 4; ++mt) {
        int row = wr * 64 + mt * 16 + mn;
        int chunk = kk * 4 + q4;
        af[mt] = *(const bf16x8*)(&Abuf[row * 128 + (chunk ^ (row & 7)) * 16]);
      }
#pragma unroll
      for (int nt = 0; nt < 4; ++nt) {
        int row = wc * 64 + nt * 16 + mn;
        int chunk = kk * 4 + q4;
        bfv[nt] = *(const bf16x8*)(&Bbuf[row * 128 + (chunk ^ (row & 7)) * 16]);
      }
#pragma unroll
      for (int mt = 0; mt < 4; ++mt)
#pragma unroll
        for (int nt = 0; nt < 4; ++nt)
          acc[mt][nt] = __builtin_amdgcn_mfma_f32_16x16x32_bf16(af[mt], bfv[nt], acc[mt][nt], 0, 0, 0);
    }
  }
  __syncthreads();
  // epilogue: per-wave LDS bounce (rows padded to 144B), coalesced bf16 store
  unsigned char* eb = shm + w * 9216;
#pragma unroll
  for (int mt = 0; mt < 4; ++mt)
#pragma unroll
    for (int nt = 0; nt < 4; ++nt)
#pragma unroll
      for (int r = 0; r < 4; ++r) {
        int rl = mt * 16 + q4 * 4 + r;
        int cl = nt * 16 + mn;
        *(unsigned short*)(&eb[rl * 144 + cl * 2]) = f2bf(acc[mt][nt][r]);
      }
  char* Mg = (char*)m_t + cbase + (long)(ti * 128 + wr * 64) * 1024 + (tj * 128 + wc * 64) * 2;
#pragma unroll
  for (int it = 0; it < 8; ++it) {
    int rl = it * 8 + (lane >> 3), cc = lane & 7;
    *(int4*)(Mg + (long)rl * 1024 + cc * 16) = *(const int4*)(&eb[rl * 144 + cc * 16]);
  }
}

// ---------------------------------------------------------------------------
// K4: per 64-row tile: LN(m) over c, m_ln @ Wpo, * g * mask -> dz fp32
// Transpose uses e-rotation so simultaneous lane writes hit distinct bank rows.
// ---------------------------------------------------------------------------
__global__ __launch_bounds__(256) void k_out(const unsigned short* __restrict__ m_t,
                                             const unsigned short* __restrict__ gbuf,
                                             const unsigned short* __restrict__ Wt,
                                             const int* __restrict__ maskp,
                                             const float* __restrict__ lnw,
                                             const float* __restrict__ lnb,
                                             float* __restrict__ out) {
  __shared__ unsigned char mln[64 * 272];   // [row][c] bf16, padded rows
  __shared__ float obuf[64 * 132];          // [row][c] fp32, padded rows
  __shared__ float lw[128], lb[128], mk[64];
  const int t = threadIdx.x;
  const long r0 = (long)blockIdx.x * 64;

  // stage + transpose m tile: m_t[c][r0+..] -> mln[row][c], e-rotated
#pragma unroll
  for (int it = 0; it < 4; ++it) {
    int chunk = it * 256 + t;
    int c = chunk >> 3, cc = chunk & 7;
    int4 rv = *(const int4*)((const char*)m_t + (long)c * 524288 + r0 * 2 + cc * 16);
    const unsigned short* rp = (const unsigned short*)&rv;
#pragma unroll
    for (int e = 0; e < 8; ++e) {
      int er = (e + cc) & 7;   // rotate: rows mod 8 distinct across lanes
      *(unsigned short*)(&mln[(cc * 8 + er) * 272 + c * 2]) = rp[er];
    }
  }
  if (t < 128) { lw[t] = lnw[t]; lb[t] = lnb[t]; }
  if (t < 64) mk[t] = (float)maskp[r0 + t];
  __syncthreads();

  {  // LayerNorm over c: 4 threads per row; write m_ln back in place (bf16)
    int row = t >> 2, part = t & 3;
    float xv[32];
    float s = 0.f, q = 0.f;
#pragma unroll
    for (int jj = 0; jj < 16; ++jj) {
      unsigned u = *(const unsigned*)(&mln[row * 272 + part * 64 + jj * 4]);
      float x0 = bf2f((unsigned short)(u & 0xffff));
      float x1 = bf2f((unsigned short)(u >> 16));
      xv[2 * jj] = x0; xv[2 * jj + 1] = x1;
      s += x0 + x1; q += x0 * x0 + x1 * x1;
    }
    s += __shfl_xor(s, 1); q += __shfl_xor(q, 1);
    s += __shfl_xor(s, 2); q += __shfl_xor(q, 2);
    float mu = s * (1.f / 128.f);
    float var = q * (1.f / 128.f) - mu * mu;
    float rs = rsqrtf(var + EPSV);
#pragma unroll
    for (int jj = 0; jj < 16; ++jj) {
      int c = part * 32 + 2 * jj;
      unsigned short h0 = f2bf((xv[2 * jj] - mu) * rs * lw[c] + lb[c]);
      unsigned short h1 = f2bf((xv[2 * jj + 1] - mu) * rs * lw[c + 1] + lb[c + 1]);
      *(unsigned*)(&mln[row * 272 + c * 2]) = (unsigned)h0 | ((unsigned)h1 << 16);
    }
  }
  __syncthreads();

  // GEMM: m_ln @ Wpo -> obuf (raw acc)
  const int w = t >> 6, lane = t & 63;
  const int mn = lane & 15, q4 = lane >> 4;
  bf16x8 afr[4];
#pragma unroll
  for (int kk = 0; kk < 4; ++kk)
    afr[kk] = *(const bf16x8*)(&mln[(w * 16 + mn) * 272 + kk * 64 + q4 * 16]);
  const unsigned short* Wp = Wt + 5 * 16384;
#pragma unroll 1
  for (int nt = 0; nt < 8; ++nt) {
    f32x4 acc = {0.f, 0.f, 0.f, 0.f};
#pragma unroll
    for (int kk = 0; kk < 4; ++kk) {
      bf16x8 bfr = *(const bf16x8*)(Wp + (nt * 16 + mn) * 128 + kk * 32 + q4 * 8);
      acc = __builtin_amdgcn_mfma_f32_16x16x32_bf16(afr[kk], bfr, acc, 0, 0, 0);
    }
    const int cl = nt * 16 + mn;
#pragma unroll
    for (int r = 0; r < 4; ++r)
      obuf[(w * 16 + q4 * 4 + r) * 132 + cl] = acc[r];
  }
  __syncthreads();

  // out = obuf * g * mask (coalesced; g read as bf16x4 chunks)
#pragma unroll
  for (int it = 0; it < 8; ++it) {
    int chunk = it * 256 + t;
    int row = chunk >> 5, cc = chunk & 31;
    float4 v = *(const float4*)(&obuf[row * 132 + cc * 4]);
    uint2 gp = *(const uint2*)((const char*)gbuf + (r0 + row) * 256 + cc * 8);
    float mval = mk[row];
    v.x *= bf2f((unsigned short)(gp.x & 0xffff)) * mval;
    v.y *= bf2f((unsigned short)(gp.x >> 16)) * mval;
    v.z *= bf2f((unsigned short)(gp.y & 0xffff)) * mval;
    v.w *= bf2f((unsigned short)(gp.y >> 16)) * mval;
    *(float4*)(out + (r0 + row) * 128 + cc * 4) = v;
  }
}

// ---------------------------------------------------------------------------
extern "C" void kernel_launch(void* const* d_in, const int* in_sizes, int n_in,
                              void* d_out, int out_size, void* d_ws, size_t ws_size,
                              hipStream_t stream) {
  const float* z    = (const float*)d_in[0];
  const int* maskp  = (const int*)d_in[1];
  const float* lniw = (const float*)d_in[2];
  const float* lnib = (const float*)d_in[3];
  const float* lnow = (const float*)d_in[4];
  const float* lnob = (const float*)d_in[5];
  const float* Wpa  = (const float*)d_in[6];
  const float* Wga  = (const float*)d_in[7];
  const float* Wpb  = (const float*)d_in[8];
  const float* Wgb  = (const float*)d_in[9];
  const float* Wgo  = (const float*)d_in[10];
  const float* Wpo  = (const float*)d_in[11];
  float* out = (float*)d_out;

  char* ws = (char*)d_ws;
  unsigned short* a_t = (unsigned short*)(ws);                 // bf16 [128][262144]
  unsigned short* b_t = (unsigned short*)(ws + 67108864);      // bf16 [128][262144]
  unsigned short* g   = (unsigned short*)(ws + 134217728);     // bf16 [262144][128]
  unsigned short* m_t = (unsigned short*)(ws + 201326592);     // bf16 [128][262144]
  unsigned short* Wt  = (unsigned short*)(ws + 268435456);     // 6 x [128][128] bf16

  k_prep<<<384, 256, 0, stream>>>(Wpa, Wga, Wpb, Wgb, Wgo, Wpo, Wt);
  k_proj<<<2048, 256, 0, stream>>>(z, lniw, lnib, Wt, maskp, a_t, b_t, g);
  k_einsum<<<2048, 256, 0, stream>>>(a_t, b_t, m_t);
  k_out<<<4096, 256, 0, stream>>>(m_t, g, Wt, maskp, lnow, lnob, out);
}

// Round 4
// 531.662 us; speedup vs baseline: 1.3697x; 1.2362x over previous
//
#include <hip/hip_runtime.h>
#include <stdint.h>

#define LDIM 512
#define LLTOT 262144            // 512*512
#define EPSV 1e-5f

typedef short bf16x8 __attribute__((ext_vector_type(8)));
typedef float f32x4 __attribute__((ext_vector_type(4)));

__device__ __forceinline__ unsigned short f2bf(float f) {
  union { float f; unsigned u; } v; v.f = f;
  unsigned r = v.u + 0x7FFFu + ((v.u >> 16) & 1u);   // RNE
  return (unsigned short)(r >> 16);
}
__device__ __forceinline__ float bf2f(unsigned short h) {
  union { unsigned u; float f; } v; v.u = ((unsigned)h) << 16;
  return v.f;
}
__device__ __forceinline__ float sigm(float x) { return 1.0f / (1.0f + __expf(-x)); }

// Fragment-major layout for a/b intermediates (the einsum's operands):
//   element (ch, i, k) lives at
//   ch*524288 + (k>>5)*32768 + (i>>4)*1024 + ((i&15)*4 + ((k>>3)&3))*16 + (k&7)*2
// One (ch, k32, i16) chunk = 1 KB = exactly one wave's MFMA fragment load.

// ---------------------------------------------------------------------------
// K0: weights fp32 [c][o] -> bf16 transposed [o][c].  Order: ga,pa,gb,pb,go,po
// ---------------------------------------------------------------------------
__global__ void k_prep(const float* __restrict__ Wpa, const float* __restrict__ Wga,
                       const float* __restrict__ Wpb, const float* __restrict__ Wgb,
                       const float* __restrict__ Wgo, const float* __restrict__ Wpo,
                       unsigned short* __restrict__ Wt) {
  int t = blockIdx.x * blockDim.x + threadIdx.x;     // 0..98303
  int mat = t >> 14;
  int rem = t & 16383;
  int o = rem >> 7;
  int c = rem & 127;
  const float* src;
  switch (mat) {
    case 0: src = Wga; break;
    case 1: src = Wpa; break;
    case 2: src = Wgb; break;
    case 3: src = Wpb; break;
    case 4: src = Wgo; break;
    default: src = Wpo; break;
  }
  Wt[mat * 16384 + o * 128 + c] = f2bf(src[c * 128 + o]);
}

// ---------------------------------------------------------------------------
// K1 (fused LN + projections), weights-resident.  Per block: 128 flat positions
// (one z-row i, 128 consecutive k).  a/b stored in FRAGMENT-MAJOR layout.
// ---------------------------------------------------------------------------
__global__ __launch_bounds__(256) void k_proj(const float* __restrict__ z,
                                              const float* __restrict__ lnw,
                                              const float* __restrict__ lnb,
                                              const unsigned short* __restrict__ Wt,
                                              const int* __restrict__ maskp,
                                              unsigned short* __restrict__ a_f,
                                              unsigned short* __restrict__ b_f,
                                              unsigned short* __restrict__ gout) {
  __shared__ unsigned char zbuf[128 * 272];   // rows padded 256->272B
  __shared__ float maskf[128];
  const int t = threadIdx.x;
  const int bid = blockIdx.x;
  const long r0 = (long)bid * 128;
  const int w = t >> 6, lane = t & 63;
  const int mn = lane & 15, q4 = lane >> 4;
  // fragment-layout constants for this block (i fixed, k0 = start col)
  const int k0 = (bid & 3) * 128;
  const int i16 = bid >> 6;            // (i>>4), i = bid>>2
  const int irem = (bid >> 2) & 15;    // i & 15

  if (t < 128) maskf[t] = (float)maskp[r0 + t];

  // fused input LayerNorm: each wave handles 32 rows; lane holds 2 channels
  const float lw0 = lnw[2 * lane], lw1 = lnw[2 * lane + 1];
  const float lb0 = lnb[2 * lane], lb1 = lnb[2 * lane + 1];
#pragma unroll 2
  for (int rr = 0; rr < 32; rr += 4) {
    float2 v[4];
#pragma unroll
    for (int i = 0; i < 4; ++i)
      v[i] = ((const float2*)(z + (r0 + w * 32 + rr + i) * 128))[lane];
#pragma unroll
    for (int i = 0; i < 4; ++i) {
      float s = v[i].x + v[i].y, q = v[i].x * v[i].x + v[i].y * v[i].y;
#pragma unroll
      for (int off = 32; off; off >>= 1) { s += __shfl_xor(s, off); q += __shfl_xor(q, off); }
      float mu = s * (1.0f / 128.0f);
      float rs = rsqrtf(q * (1.0f / 128.0f) - mu * mu + EPSV);
      ushort2 o;
      o.x = f2bf((v[i].x - mu) * rs * lw0 + lb0);
      o.y = f2bf((v[i].y - mu) * rs * lw1 + lb1);
      ((ushort2*)&zbuf[(w * 32 + rr + i) * 272])[lane] = o;
    }
  }
  __syncthreads();

  // phases p=0 (a), p=1 (b): gate+proj weights resident in VGPRs
#pragma unroll 1
  for (int p = 0; p < 2; ++p) {
    const unsigned short* Wg = Wt + (p * 2) * 16384;
    const unsigned short* Wp = Wt + (p * 2 + 1) * 16384;
    unsigned short* dst = p ? b_f : a_f;
    bf16x8 wg[2][4], wp[2][4];
#pragma unroll
    for (int ntl = 0; ntl < 2; ++ntl)
#pragma unroll
      for (int kk = 0; kk < 4; ++kk) {
        const int o = (w * 2 + ntl) * 16 + mn;
        wg[ntl][kk] = *(const bf16x8*)(Wg + o * 128 + kk * 32 + q4 * 8);
        wp[ntl][kk] = *(const bf16x8*)(Wp + o * 128 + kk * 32 + q4 * 8);
      }
#pragma unroll 1
    for (int rg = 0; rg < 8; ++rg) {
      bf16x8 afr[4];
#pragma unroll
      for (int kk = 0; kk < 4; ++kk)
        afr[kk] = *(const bf16x8*)(&zbuf[(rg * 16 + mn) * 272 + kk * 64 + q4 * 16]);
      f32x4 aG[2] = {{0.f,0.f,0.f,0.f},{0.f,0.f,0.f,0.f}};
      f32x4 aP[2] = {{0.f,0.f,0.f,0.f},{0.f,0.f,0.f,0.f}};
#pragma unroll
      for (int kk = 0; kk < 4; ++kk)
#pragma unroll
        for (int ntl = 0; ntl < 2; ++ntl) {
          aG[ntl] = __builtin_amdgcn_mfma_f32_16x16x32_bf16(afr[kk], wg[ntl][kk], aG[ntl], 0, 0, 0);
          aP[ntl] = __builtin_amdgcn_mfma_f32_16x16x32_bf16(afr[kk], wp[ntl][kk], aP[ntl], 0, 0, 0);
        }
      const int rowb = rg * 16 + q4 * 4;        // k-offset within block (4 consec)
      const int kpos = k0 + rowb;               // global k of first element
      const int kc = kpos >> 5;
      const int cell = (irem * 4 + ((kpos >> 3) & 3)) * 16 + (kpos & 7) * 2;
#pragma unroll
      for (int ntl = 0; ntl < 2; ++ntl) {
        const int c = (w * 2 + ntl) * 16 + mn;
        unsigned short hv[4];
#pragma unroll
        for (int r = 0; r < 4; ++r)
          hv[r] = f2bf(sigm(aG[ntl][r]) * aP[ntl][r] * maskf[rowb + r]);
        uint2 pk;
        pk.x = (unsigned)hv[0] | ((unsigned)hv[1] << 16);
        pk.y = (unsigned)hv[2] | ((unsigned)hv[3] << 16);
        *(uint2*)((char*)dst + (long)c * 524288 + kc * 32768 + i16 * 1024 + cell) = pk;
      }
    }
  }

  {  // g phase: g = sigmoid(zln @ Wgo) -> gout[row][c] (direct 2B stores, L2 merges)
    const unsigned short* Wgp = Wt + 4 * 16384;
    bf16x8 wg[2][4];
#pragma unroll
    for (int ntl = 0; ntl < 2; ++ntl)
#pragma unroll
      for (int kk = 0; kk < 4; ++kk)
        wg[ntl][kk] = *(const bf16x8*)(Wgp + ((w * 2 + ntl) * 16 + mn) * 128 + kk * 32 + q4 * 8);
#pragma unroll 1
    for (int rg = 0; rg < 8; ++rg) {
      bf16x8 afr[4];
#pragma unroll
      for (int kk = 0; kk < 4; ++kk)
        afr[kk] = *(const bf16x8*)(&zbuf[(rg * 16 + mn) * 272 + kk * 64 + q4 * 16]);
      f32x4 aG[2] = {{0.f,0.f,0.f,0.f},{0.f,0.f,0.f,0.f}};
#pragma unroll
      for (int kk = 0; kk < 4; ++kk)
#pragma unroll
        for (int ntl = 0; ntl < 2; ++ntl)
          aG[ntl] = __builtin_amdgcn_mfma_f32_16x16x32_bf16(afr[kk], wg[ntl][kk], aG[ntl], 0, 0, 0);
      const int rowb = rg * 16 + q4 * 4;
#pragma unroll
      for (int ntl = 0; ntl < 2; ++ntl) {
        const int c = (w * 2 + ntl) * 16 + mn;
#pragma unroll
        for (int r = 0; r < 4; ++r)
          gout[(r0 + rowb + r) * 128 + c] = f2bf(sigm(aG[ntl][r]));
      }
    }
  }
}

// ---------------------------------------------------------------------------
// K3: per-channel GEMM  m_c = a_c @ b_c^T from FRAGMENT-MAJOR operands.
// NO LDS staging, NO barriers: each wave loads its MFMA fragments directly
// from global (one coalesced 1-KB load per fragment), double-buffered so the
// next k-chunk's 8 loads are in flight during the current 16 MFMAs.  Latency
// hidden by fine-grained vmcnt + 12 waves/CU.  XCD-affinity swizzle for L2.
// ---------------------------------------------------------------------------
__global__ __launch_bounds__(256) void k_einsum(const unsigned short* __restrict__ af_g,
                                                const unsigned short* __restrict__ bf_g,
                                                unsigned short* __restrict__ m_t) {
  __shared__ unsigned char shm[36864];   // epilogue bounce only (per-wave 9216B)
  const int t = threadIdx.x;
  const int w = t >> 6, lane = t & 63;
  const int bid = blockIdx.x;
  const int xcd = bid & 7;               // round-robin bid%8 -> XCD
  const int j = bid >> 3;
  const int ch = xcd * 16 + (j >> 4);    // 16 channels per XCD
  const int tile = j & 15;
  const int ti = tile >> 2, tj = tile & 3;
  const int wr = w >> 1, wc = w & 1;
  const int mn = lane & 15, q4 = lane >> 4;
  const int loff = (mn * 4 + q4) * 16;   // cell order: (i&15)*4 + k-subchunk
  const char* Af = (const char*)af_g + (long)ch * 524288 + (ti * 8 + wr * 4) * 1024 + loff;
  const char* Bf = (const char*)bf_g + (long)ch * 524288 + (tj * 8 + wc * 4) * 1024 + loff;

  f32x4 acc[4][4];
#pragma unroll
  for (int i = 0; i < 4; ++i)
#pragma unroll
    for (int jj = 0; jj < 4; ++jj) acc[i][jj] = (f32x4){0.f, 0.f, 0.f, 0.f};

  bf16x8 afr[2][4], bfr[2][4];
#define LOADFRAG(buf, k32)                                                    \
  {                                                                           \
    _Pragma("unroll")                                                         \
    for (int mt = 0; mt < 4; ++mt)                                            \
      afr[buf][mt] = *(const bf16x8*)(Af + (k32) * 32768 + mt * 1024);        \
    _Pragma("unroll")                                                         \
    for (int nt = 0; nt < 4; ++nt)                                            \
      bfr[buf][nt] = *(const bf16x8*)(Bf + (k32) * 32768 + nt * 1024);        \
  }
#define MFMABLK(buf)                                                          \
  {                                                                           \
    _Pragma("unroll")                                                         \
    for (int mt = 0; mt < 4; ++mt)                                            \
      _Pragma("unroll")                                                       \
      for (int nt = 0; nt < 4; ++nt)                                          \
        acc[mt][nt] = __builtin_amdgcn_mfma_f32_16x16x32_bf16(                \
            afr[buf][mt], bfr[buf][nt], acc[mt][nt], 0, 0, 0);                \
  }

  LOADFRAG(0, 0)
#pragma unroll 1
  for (int k32 = 0; k32 < 14; k32 += 2) {
    LOADFRAG(1, k32 + 1)
    MFMABLK(0)
    LOADFRAG(0, k32 + 2)
    MFMABLK(1)
  }
  LOADFRAG(1, 15)
  MFMABLK(0)
  MFMABLK(1)
#undef LOADFRAG
#undef MFMABLK

  // epilogue: per-wave LDS bounce (rows padded to 144B), coalesced bf16 store.
  // eb is wave-private -> no __syncthreads needed.
  unsigned char* eb = shm + w * 9216;
#pragma unroll
  for (int mt = 0; mt < 4; ++mt)
#pragma unroll
    for (int nt = 0; nt < 4; ++nt)
#pragma unroll
      for (int r = 0; r < 4; ++r) {
        int rl = mt * 16 + q4 * 4 + r;
        int cl = nt * 16 + mn;
        *(unsigned short*)(&eb[rl * 144 + cl * 2]) = f2bf(acc[mt][nt][r]);
      }
  char* Mg = (char*)m_t + (long)ch * 524288 +
             (long)(ti * 128 + wr * 64) * 1024 + (tj * 128 + wc * 64) * 2;
#pragma unroll
  for (int it = 0; it < 8; ++it) {
    int rl = it * 8 + (lane >> 3), cc = lane & 7;
    *(int4*)(Mg + (long)rl * 1024 + cc * 16) = *(const int4*)(&eb[rl * 144 + cc * 16]);
  }
}

// ---------------------------------------------------------------------------
// K4: per 64-row tile: LN(m) over c, m_ln @ Wpo, * g * mask -> dz fp32
// ---------------------------------------------------------------------------
__global__ __launch_bounds__(256) void k_out(const unsigned short* __restrict__ m_t,
                                             const unsigned short* __restrict__ gbuf,
                                             const unsigned short* __restrict__ Wt,
                                             const int* __restrict__ maskp,
                                             const float* __restrict__ lnw,
                                             const float* __restrict__ lnb,
                                             float* __restrict__ out) {
  __shared__ unsigned char mln[64 * 272];   // [row][c] bf16, padded rows
  __shared__ float obuf[64 * 132];          // [row][c] fp32, padded rows
  __shared__ float lw[128], lb[128], mk[64];
  const int t = threadIdx.x;
  const long r0 = (long)blockIdx.x * 64;

  // stage + transpose m tile: m_t[c][r0+..] -> mln[row][c], e-rotated
#pragma unroll
  for (int it = 0; it < 4; ++it) {
    int chunk = it * 256 + t;
    int c = chunk >> 3, cc = chunk & 7;
    int4 rv = *(const int4*)((const char*)m_t + (long)c * 524288 + r0 * 2 + cc * 16);
    const unsigned short* rp = (const unsigned short*)&rv;
#pragma unroll
    for (int e = 0; e < 8; ++e) {
      int er = (e + cc) & 7;   // rotate: rows mod 8 distinct across lanes
      *(unsigned short*)(&mln[(cc * 8 + er) * 272 + c * 2]) = rp[er];
    }
  }
  if (t < 128) { lw[t] = lnw[t]; lb[t] = lnb[t]; }
  if (t < 64) mk[t] = (float)maskp[r0 + t];
  __syncthreads();

  {  // LayerNorm over c: 4 threads per row; write m_ln back in place (bf16)
    int row = t >> 2, part = t & 3;
    float xv[32];
    float s = 0.f, q = 0.f;
#pragma unroll
    for (int jj = 0; jj < 16; ++jj) {
      unsigned u = *(const unsigned*)(&mln[row * 272 + part * 64 + jj * 4]);
      float x0 = bf2f((unsigned short)(u & 0xffff));
      float x1 = bf2f((unsigned short)(u >> 16));
      xv[2 * jj] = x0; xv[2 * jj + 1] = x1;
      s += x0 + x1; q += x0 * x0 + x1 * x1;
    }
    s += __shfl_xor(s, 1); q += __shfl_xor(q, 1);
    s += __shfl_xor(s, 2); q += __shfl_xor(q, 2);
    float mu = s * (1.f / 128.f);
    float var = q * (1.f / 128.f) - mu * mu;
    float rs = rsqrtf(var + EPSV);
#pragma unroll
    for (int jj = 0; jj < 16; ++jj) {
      int c = part * 32 + 2 * jj;
      unsigned short h0 = f2bf((xv[2 * jj] - mu) * rs * lw[c] + lb[c]);
      unsigned short h1 = f2bf((xv[2 * jj + 1] - mu) * rs * lw[c + 1] + lb[c + 1]);
      *(unsigned*)(&mln[row * 272 + c * 2]) = (unsigned)h0 | ((unsigned)h1 << 16);
    }
  }
  __syncthreads();

  // GEMM: m_ln @ Wpo -> obuf (raw acc)
  const int w = t >> 6, lane = t & 63;
  const int mn = lane & 15, q4 = lane >> 4;
  bf16x8 afr[4];
#pragma unroll
  for (int kk = 0; kk < 4; ++kk)
    afr[kk] = *(const bf16x8*)(&mln[(w * 16 + mn) * 272 + kk * 64 + q4 * 16]);
  const unsigned short* Wp = Wt + 5 * 16384;
#pragma unroll 1
  for (int nt = 0; nt < 8; ++nt) {
    f32x4 acc = {0.f, 0.f, 0.f, 0.f};
#pragma unroll
    for (int kk = 0; kk < 4; ++kk) {
      bf16x8 bfr = *(const bf16x8*)(Wp + (nt * 16 + mn) * 128 + kk * 32 + q4 * 8);
      acc = __builtin_amdgcn_mfma_f32_16x16x32_bf16(afr[kk], bfr, acc, 0, 0, 0);
    }
    const int cl = nt * 16 + mn;
#pragma unroll
    for (int r = 0; r < 4; ++r)
      obuf[(w * 16 + q4 * 4 + r) * 132 + cl] = acc[r];
  }
  __syncthreads();

  // out = obuf * g * mask (coalesced; g read as bf16x4 chunks)
#pragma unroll
  for (int it = 0; it < 8; ++it) {
    int chunk = it * 256 + t;
    int row = chunk >> 5, cc = chunk & 31;
    float4 v = *(const float4*)(&obuf[row * 132 + cc * 4]);
    uint2 gp = *(const uint2*)((const char*)gbuf + (r0 + row) * 256 + cc * 8);
    float mval = mk[row];
    v.x *= bf2f((unsigned short)(gp.x & 0xffff)) * mval;
    v.y *= bf2f((unsigned short)(gp.x >> 16)) * mval;
    v.z *= bf2f((unsigned short)(gp.y & 0xffff)) * mval;
    v.w *= bf2f((unsigned short)(gp.y >> 16)) * mval;
    *(float4*)(out + (r0 + row) * 128 + cc * 4) = v;
  }
}

// ---------------------------------------------------------------------------
extern "C" void kernel_launch(void* const* d_in, const int* in_sizes, int n_in,
                              void* d_out, int out_size, void* d_ws, size_t ws_size,
                              hipStream_t stream) {
  const float* z    = (const float*)d_in[0];
  const int* maskp  = (const int*)d_in[1];
  const float* lniw = (const float*)d_in[2];
  const float* lnib = (const float*)d_in[3];
  const float* lnow = (const float*)d_in[4];
  const float* lnob = (const float*)d_in[5];
  const float* Wpa  = (const float*)d_in[6];
  const float* Wga  = (const float*)d_in[7];
  const float* Wpb  = (const float*)d_in[8];
  const float* Wgb  = (const float*)d_in[9];
  const float* Wgo  = (const float*)d_in[10];
  const float* Wpo  = (const float*)d_in[11];
  float* out = (float*)d_out;

  char* ws = (char*)d_ws;
  unsigned short* a_f = (unsigned short*)(ws);                 // bf16 frag-major [128 ch][512KB]
  unsigned short* b_f = (unsigned short*)(ws + 67108864);      // bf16 frag-major
  unsigned short* g   = (unsigned short*)(ws + 134217728);     // bf16 [262144][128]
  unsigned short* m_t = (unsigned short*)(ws + 201326592);     // bf16 [128][262144]
  unsigned short* Wt  = (unsigned short*)(ws + 268435456);     // 6 x [128][128] bf16

  k_prep<<<384, 256, 0, stream>>>(Wpa, Wga, Wpb, Wgb, Wgo, Wpo, Wt);
  k_proj<<<2048, 256, 0, stream>>>(z, lniw, lnib, Wt, maskp, a_f, b_f, g);
  k_einsum<<<2048, 256, 0, stream>>>(a_f, b_f, m_t);
  k_out<<<4096, 256, 0, stream>>>(m_t, g, Wt, maskp, lnow, lnob, out);
}